// Round 5
// baseline (245.112 us; speedup 1.0000x reference)
//
#include <hip/hip_runtime.h>

// SeaThru-NeRF RGB renderer forward pass, round 8.
//
// R7 POST-MORTEM: input-only asm pins were satisfied by REMATERIALIZATION --
// compiler issued load->pin serially in 4 regs, then re-loaded values at use
// sites (VGPR stayed 40, time stayed 96us). Four structures (shuffle/LDS/DPP/
// pins) all pinned at ~96us / ~1.8 TB/s with every pipe <35% busy; coalescing
// (R4) and occupancy (49-71%) proven irrelevant. Remaining theory: per-wave
// loads execute near-serially and short-lived waves never build the ~2.4MB
// chip-wide in-flight needed to saturate HBM.
//
// FIX 1: ONE atomic mega-load -- all 14 global_load_dwordx4 PLUS the
// s_waitcnt vmcnt(0) inside a SINGLE asm volatile with earlyclobber outputs.
// Indivisible from the compiler's PoV: cannot sink/split/serialize/remat.
// 14 KB guaranteed in flight per wave per iteration.
// FIX 2: persistent waves -- 512 blocks x 4 waves = 2048 waves, all resident
// at 2 waves/SIMD (launch_bounds(256,2)), each grid-striding 8 rays. Startup
// paid once; burst/compute alternation across waves keeps ~50KB/CU in flight.
//
// Compute math identical to verified R5 (DPP scans, fused log2 attenuation).

#define LOG2E 1.4426950408889634f

typedef float f4 __attribute__((ext_vector_type(4)));

__device__ __forceinline__ float clip01(float x) {
    return fminf(fmaxf(x, 0.0f), 1.0f);
}

// DPP move (old=0, bank_mask=0xf). Template params keep builtin args ICE.
template <int CTRL, int ROW_MASK, bool BND>
__device__ __forceinline__ float dpp_mov(float v) {
    return __int_as_float(__builtin_amdgcn_update_dpp(
        0, __float_as_int(v), CTRL, ROW_MASK, 0xf, BND));
}

// N-wide interleaved wave64 INCLUSIVE add-scan, entirely on the VALU pipe.
template <int N>
__device__ __forceinline__ void wave_iscan(float (&v)[N]) {
#pragma unroll
    for (int j = 0; j < N; ++j) v[j] += dpp_mov<0x111, 0xf, true>(v[j]);
#pragma unroll
    for (int j = 0; j < N; ++j) v[j] += dpp_mov<0x112, 0xf, true>(v[j]);
#pragma unroll
    for (int j = 0; j < N; ++j) v[j] += dpp_mov<0x114, 0xf, true>(v[j]);
#pragma unroll
    for (int j = 0; j < N; ++j) v[j] += dpp_mov<0x118, 0xf, true>(v[j]);
#pragma unroll
    for (int j = 0; j < N; ++j) v[j] += dpp_mov<0x142, 0xa, false>(v[j]);
#pragma unroll
    for (int j = 0; j < N; ++j) v[j] += dpp_mov<0x143, 0xc, false>(v[j]);
}

__global__ __launch_bounds__(256, 2) void seathru_render(
    const float* __restrict__ g_orgb,   // [R,S,3] object_rgbs
    const float* __restrict__ g_mrgb,   // [R,S,3] medium_rgbs
    const float* __restrict__ g_dc,     // [R,S,3] direct_coeffs
    const float* __restrict__ g_bc,     // [R,S,3] backscatter_coeffs
    const float* __restrict__ g_den,    // [R,S,1] densities
    const float* __restrict__ g_del,    // [R,S,1] deltas
    float* __restrict__ out, int R)
{
    const int S = 256;
    const int lane   = threadIdx.x & 63;
    const int wid    = blockIdx.x * 4 + (threadIdx.x >> 6);  // wave id
    const int stride = gridDim.x * 4;                        // total waves
    const size_t RS  = (size_t)R * S;

    float* outT = out + (size_t)12 * R;      // object_transmittance [R,S]
    float* outA = outT + RS;                 // object_alphas
    float* outW = outA + RS;                 // object_weights

    for (int ray = wid; ray < R; ray += stride) {
        const size_t b3 = (size_t)ray * (S * 3);
        const size_t b1 = (size_t)ray * S;

        // per-lane base addresses (lane owns samples 4*lane .. 4*lane+3)
        const float* p_or = g_orgb + b3 + (size_t)lane * 12;
        const float* p_dc = g_dc   + b3 + (size_t)lane * 12;
        const float* p_bc = g_bc   + b3 + (size_t)lane * 12;
        const float* p_mr = g_mrgb + b3 + (size_t)lane * 12;
        const float* p_dl = g_del  + b1 + (size_t)lane * 4;
        const float* p_dn = g_den  + b1 + (size_t)lane * 4;

        // ---- ATOMIC MEGA-LOAD: 14 dwordx4 issued back-to-back + one drain.
        //      Single asm block => compiler cannot split/sink/remat; outputs
        //      earlyclobber => no dest/address aliasing; waitcnt inside =>
        //      outputs valid at asm exit.
        f4 orA, orB, orC, dcA, dcB, dcC, bcA, bcB, bcC, mrA, mrB, mrC, dl4, dn4;
        asm volatile(
            "global_load_dwordx4 %0,  %14, off\n\t"
            "global_load_dwordx4 %1,  %14, off offset:16\n\t"
            "global_load_dwordx4 %2,  %14, off offset:32\n\t"
            "global_load_dwordx4 %3,  %15, off\n\t"
            "global_load_dwordx4 %4,  %15, off offset:16\n\t"
            "global_load_dwordx4 %5,  %15, off offset:32\n\t"
            "global_load_dwordx4 %6,  %16, off\n\t"
            "global_load_dwordx4 %7,  %16, off offset:16\n\t"
            "global_load_dwordx4 %8,  %16, off offset:32\n\t"
            "global_load_dwordx4 %9,  %17, off\n\t"
            "global_load_dwordx4 %10, %17, off offset:16\n\t"
            "global_load_dwordx4 %11, %17, off offset:32\n\t"
            "global_load_dwordx4 %12, %18, off\n\t"
            "global_load_dwordx4 %13, %19, off\n\t"
            "s_waitcnt vmcnt(0)"
            : "=&v"(orA), "=&v"(orB), "=&v"(orC),
              "=&v"(dcA), "=&v"(dcB), "=&v"(dcC),
              "=&v"(bcA), "=&v"(bcB), "=&v"(bcC),
              "=&v"(mrA), "=&v"(mrB), "=&v"(mrC),
              "=&v"(dl4), "=&v"(dn4)
            : "v"(p_or), "v"(p_dc), "v"(p_bc), "v"(p_mr), "v"(p_dl), "v"(p_dn));

        // ---- unpack (static indices; stays in registers) ----
        const float dcv[12] = {dcA[0], dcA[1], dcA[2], dcA[3],
                               dcB[0], dcB[1], dcB[2], dcB[3],
                               dcC[0], dcC[1], dcC[2], dcC[3]};
        const float bcv[12] = {bcA[0], bcA[1], bcA[2], bcA[3],
                               bcB[0], bcB[1], bcB[2], bcB[3],
                               bcC[0], bcC[1], bcC[2], bcC[3]};
        const float orv[12] = {orA[0], orA[1], orA[2], orA[3],
                               orB[0], orB[1], orB[2], orB[3],
                               orC[0], orC[1], orC[2], orC[3]};
        const float mrv[12] = {mrA[0], mrA[1], mrA[2], mrA[3],
                               mrB[0], mrB[1], mrB[2], mrB[3],
                               mrC[0], mrC[1], mrC[2], mrC[3]};

        const float del[4] = {dl4[0] * LOG2E, dl4[1] * LOG2E,
                              dl4[2] * LOG2E, dl4[3] * LOG2E};
        const float den[4] = {dn4[0], dn4[1], dn4[2], dn4[3]};

        // ---- thread-local pre-pass ----
        float dd[4], alpha[4];
#pragma unroll
        for (int i = 0; i < 4; ++i) {
            dd[i]    = del[i] * den[i];
            alpha[i] = 1.0f - exp2f(-dd[i]);
        }

        float aorv[12];   // alpha * object_rgb
        float mamr[12];   // medium_alpha * medium_rgb
#pragma unroll
        for (int i = 0; i < 4; ++i) {
#pragma unroll
            for (int c = 0; c < 3; ++c) {
                aorv[i * 3 + c] = alpha[i] * orv[i * 3 + c];
                const float bsd = bcv[i * 3 + c] * del[i];
                mamr[i * 3 + c] = (1.0f - exp2f(-bsd)) * mrv[i * 3 + c];
            }
        }

        // ---- serial (intra-thread) exclusive prefixes for 7 fused scans ----
        float ser[7][4];
        float run[7];
#pragma unroll
        for (int q = 0; q < 7; ++q) run[q] = 0.0f;
#pragma unroll
        for (int i = 0; i < 4; ++i) {
            ser[0][i] = run[0]; run[0] += dd[i];
#pragma unroll
            for (int c = 0; c < 3; ++c) {
                ser[1 + c][i] = run[1 + c]; run[1 + c] += dd[i] + dcv[i * 3 + c] * del[i];
                ser[4 + c][i] = run[4 + c]; run[4 + c] += dd[i] + bcv[i * 3 + c] * del[i];
            }
        }

        // ---- 7-wide interleaved DPP wave scan of the thread totals ----
        float sc[7];
#pragma unroll
        for (int q = 0; q < 7; ++q) sc[q] = run[q];
        wave_iscan<7>(sc);
        float off[7];
#pragma unroll
        for (int q = 0; q < 7; ++q) off[q] = sc[q] - run[q];  // wave-exclusive

        // ---- per-sample outputs ----
        float T[4], w[4];
#pragma unroll
        for (int i = 0; i < 4; ++i) {
            T[i] = exp2f(-(off[0] + ser[0][i]));
            w[i] = T[i] * alpha[i];
        }
        {
            float4 t4 = {T[0], T[1], T[2], T[3]};
            float4 a4 = {alpha[0], alpha[1], alpha[2], alpha[3]};
            float4 w4 = {w[0], w[1], w[2], w[3]};
            *((float4*)(outT + b1) + lane) = t4;
            *((float4*)(outA + b1) + lane) = a4;
            *((float4*)(outW + b1) + lane) = w4;
        }

        // ---- per-thread contributions to the 10 per-ray sums ----
        float acc[10];
#pragma unroll
        for (int c = 0; c < 3; ++c) {
            float ad = 0.0f, ab = 0.0f, ar = 0.0f;
#pragma unroll
            for (int i = 0; i < 4; ++i) {
                ad += exp2f(-(off[1 + c] + ser[1 + c][i])) * aorv[i * 3 + c];
                ab += exp2f(-(off[4 + c] + ser[4 + c][i])) * mamr[i * 3 + c];
                ar += T[i] * aorv[i * 3 + c];
            }
            acc[c]     = ad;   // direct
            acc[3 + c] = ab;   // backscatter
            acc[6 + c] = ar;   // restored
        }
        acc[9] = w[0] + w[1] + w[2] + w[3];  // object mask

        // ---- 10-wide interleaved DPP reduction (lane 63 holds totals) ----
        wave_iscan<10>(acc);

        if (lane == 63) {
            float* rgb  = out;                                  // [R,3]
            float* rest = out + (size_t)3 * R;                  // [R,3]
            float* dir  = out + (size_t)6 * R;                  // [R,3]
            float* bs   = out + (size_t)9 * R;                  // [R,3]
            float* dc0  = out + (size_t)12 * R + 3 * RS;
            float* bc0  = dc0 + (size_t)3 * R;
            float* mask = bc0 + (size_t)3 * R;                  // [R,1]
#pragma unroll
            for (int c = 0; c < 3; ++c) {
                const float d = acc[c], b = acc[3 + c];
                rgb[ray * 3 + c]  = clip01(d + b);
                dir[ray * 3 + c]  = clip01(d);
                bs[ray * 3 + c]   = clip01(b);
                rest[ray * 3 + c] = clip01(acc[6 + c]);
            }
            mask[ray] = clip01(acc[9]);
        }
        if (lane == 0) {
            float* dc0 = out + (size_t)12 * R + 3 * RS;
            float* bc0 = dc0 + (size_t)3 * R;
#pragma unroll
            for (int c = 0; c < 3; ++c) {
                dc0[ray * 3 + c] = dcv[c];   // raw sample-0 coeffs (unscaled)
                bc0[ray * 3 + c] = bcv[c];
            }
        }
    }
}

extern "C" void kernel_launch(void* const* d_in, const int* in_sizes, int n_in,
                              void* d_out, int out_size, void* d_ws, size_t ws_size,
                              hipStream_t stream) {
    const float* orgb = (const float*)d_in[0];
    const float* mrgb = (const float*)d_in[1];
    const float* dc   = (const float*)d_in[2];
    const float* bc   = (const float*)d_in[3];
    const float* den  = (const float*)d_in[4];
    const float* del  = (const float*)d_in[5];

    const int S = 256;
    const int R = in_sizes[0] / (S * 3);

    // Persistent grid: 512 blocks x 4 waves = 2048 waves, exactly all-resident
    // at 2 waves/SIMD on 256 CUs; each wave grid-strides ceil(R/2048) rays.
    int nblk = 512;
    int need = (R + 3) / 4;          // one wave per ray minimum
    if (need < nblk) nblk = need;

    dim3 block(256);
    dim3 grid(nblk);
    seathru_render<<<grid, block, 0, stream>>>(orgb, mrgb, dc, bc, den, del,
                                               (float*)d_out, R);
}

// Round 7
// 240.906 us; speedup vs baseline: 1.0175x; 1.0175x over previous
//
#include <hip/hip_runtime.h>

// SeaThru-NeRF RGB renderer forward pass, round 10 (= R9 with compile fix).
//
// R8 POST-MORTEM: forced 14-wide load burst (indivisible asm, VGPR 48, occ
// 19%) changed nothing. Five structures have now varied wave count (32x),
// occupancy (19-71%), VGPR (24-48), cross-lane mech (shfl/LDS/DPP), and load
// issue -- ALL pin at 96-105us / 1.65-2.0 TB/s effective. Wave-side behavior
// is exonerated; the memory system delivers ~1.7 TB/s for this mix.
//
// THE ONE NEVER-VARIED COMPONENT: the write stream. 51 MB/dispatch of
// write-allocate stores (a) evicts input lines from the 256MB L3 that the
// 285MB working set already thrashes (FETCH=114MB =~ half the reads
// re-fetched per dispatch), and (b) write BW is a suspiciously constant
// 0.5 TB/s in every round. EXPERIMENT: nontemporal (nt) stores for the three
// per-sample [R,S] outputs -- stream to HBM without L2/L3 allocation.
// R9 failed to compile: __builtin_nontemporal_store rejects HIP's float4
// (class type). Fix: native ext_vector_type(4) payloads.
//
// Compute core = R5 exactly (best measured: 96.0us, DPP scans, fused log2).

#define LOG2E 1.4426950408889634f

typedef float nf4 __attribute__((ext_vector_type(4)));   // native vec4

__device__ __forceinline__ float clip01(float x) {
    return fminf(fmaxf(x, 0.0f), 1.0f);
}

// DPP move (old=0, bank_mask=0xf). Template params keep builtin args ICE.
template <int CTRL, int ROW_MASK, bool BND>
__device__ __forceinline__ float dpp_mov(float v) {
    return __int_as_float(__builtin_amdgcn_update_dpp(
        0, __float_as_int(v), CTRL, ROW_MASK, 0xf, BND));
}

// N-wide interleaved wave64 INCLUSIVE add-scan, entirely on the VALU pipe.
template <int N>
__device__ __forceinline__ void wave_iscan(float (&v)[N]) {
#pragma unroll
    for (int j = 0; j < N; ++j) v[j] += dpp_mov<0x111, 0xf, true>(v[j]);
#pragma unroll
    for (int j = 0; j < N; ++j) v[j] += dpp_mov<0x112, 0xf, true>(v[j]);
#pragma unroll
    for (int j = 0; j < N; ++j) v[j] += dpp_mov<0x114, 0xf, true>(v[j]);
#pragma unroll
    for (int j = 0; j < N; ++j) v[j] += dpp_mov<0x118, 0xf, true>(v[j]);
#pragma unroll
    for (int j = 0; j < N; ++j) v[j] += dpp_mov<0x142, 0xa, false>(v[j]);
#pragma unroll
    for (int j = 0; j < N; ++j) v[j] += dpp_mov<0x143, 0xc, false>(v[j]);
}

__global__ __launch_bounds__(256, 4) void seathru_render(
    const float* __restrict__ g_orgb,   // [R,S,3] object_rgbs
    const float* __restrict__ g_mrgb,   // [R,S,3] medium_rgbs
    const float* __restrict__ g_dc,     // [R,S,3] direct_coeffs
    const float* __restrict__ g_bc,     // [R,S,3] backscatter_coeffs
    const float* __restrict__ g_den,    // [R,S,1] densities
    const float* __restrict__ g_del,    // [R,S,1] deltas
    float* __restrict__ out, int R)
{
    const int S = 256;
    const int ray  = blockIdx.x * 4 + (threadIdx.x >> 6);  // wave-uniform
    const int lane = threadIdx.x & 63;
    if (ray >= R) return;

    const size_t b3 = (size_t)ray * (S * 3);
    const size_t b1 = (size_t)ray * S;
    const size_t RS = (size_t)R * S;

    // ---- loads: lane owns samples 4*lane .. 4*lane+3 ----
    float4 dl4 = *((const float4*)(g_del + b1) + lane);
    float4 dn4 = *((const float4*)(g_den + b1) + lane);

    float dcv[12], bcv[12], orv[12], mrv[12];
    {
        const float4* p = (const float4*)(g_dc + b3) + lane * 3;
        *(float4*)&dcv[0] = p[0]; *(float4*)&dcv[4] = p[1]; *(float4*)&dcv[8] = p[2];
    }
    {
        const float4* p = (const float4*)(g_bc + b3) + lane * 3;
        *(float4*)&bcv[0] = p[0]; *(float4*)&bcv[4] = p[1]; *(float4*)&bcv[8] = p[2];
    }
    {
        const float4* p = (const float4*)(g_orgb + b3) + lane * 3;
        *(float4*)&orv[0] = p[0]; *(float4*)&orv[4] = p[1]; *(float4*)&orv[8] = p[2];
    }
    {
        const float4* p = (const float4*)(g_mrgb + b3) + lane * 3;
        *(float4*)&mrv[0] = p[0]; *(float4*)&mrv[4] = p[1]; *(float4*)&mrv[8] = p[2];
    }

    const float del[4] = {dl4.x * LOG2E, dl4.y * LOG2E, dl4.z * LOG2E, dl4.w * LOG2E};
    const float den[4] = {dn4.x, dn4.y, dn4.z, dn4.w};

    // ---- thread-local pre-pass: consume orv/mrv immediately ----
    float dd[4], alpha[4];
#pragma unroll
    for (int i = 0; i < 4; ++i) {
        dd[i]    = del[i] * den[i];
        alpha[i] = 1.0f - exp2f(-dd[i]);
    }

    float aorv[12];   // alpha * object_rgb
    float mamr[12];   // medium_alpha * medium_rgb
#pragma unroll
    for (int i = 0; i < 4; ++i) {
#pragma unroll
        for (int c = 0; c < 3; ++c) {
            aorv[i * 3 + c] = alpha[i] * orv[i * 3 + c];
            const float bsd = bcv[i * 3 + c] * del[i];
            mamr[i * 3 + c] = (1.0f - exp2f(-bsd)) * mrv[i * 3 + c];
        }
    }

    // ---- serial (intra-thread) exclusive prefixes for the 7 fused scans ----
    float ser[7][4];
    float run[7];
#pragma unroll
    for (int q = 0; q < 7; ++q) run[q] = 0.0f;
#pragma unroll
    for (int i = 0; i < 4; ++i) {
        ser[0][i] = run[0]; run[0] += dd[i];
#pragma unroll
        for (int c = 0; c < 3; ++c) {
            ser[1 + c][i] = run[1 + c]; run[1 + c] += dd[i] + dcv[i * 3 + c] * del[i];
            ser[4 + c][i] = run[4 + c]; run[4 + c] += dd[i] + bcv[i * 3 + c] * del[i];
        }
    }

    // ---- 7-wide interleaved DPP wave scan of the thread totals ----
    float sc[7];
#pragma unroll
    for (int q = 0; q < 7; ++q) sc[q] = run[q];
    wave_iscan<7>(sc);
    float off[7];
#pragma unroll
    for (int q = 0; q < 7; ++q) off[q] = sc[q] - run[q];   // wave-exclusive

    // ---- per-sample outputs: NONTEMPORAL stores (no L2/L3 allocation) ----
    float T[4], w[4];
#pragma unroll
    for (int i = 0; i < 4; ++i) {
        T[i] = exp2f(-(off[0] + ser[0][i]));
        w[i] = T[i] * alpha[i];
    }

    float* outT = out + (size_t)12 * R;      // object_transmittance [R,S]
    float* outA = outT + RS;                 // object_alphas
    float* outW = outA + RS;                 // object_weights
    {
        nf4 t4 = {T[0], T[1], T[2], T[3]};
        nf4 a4 = {alpha[0], alpha[1], alpha[2], alpha[3]};
        nf4 w4 = {w[0], w[1], w[2], w[3]};
        __builtin_nontemporal_store(t4, (nf4*)(outT + b1) + lane);
        __builtin_nontemporal_store(a4, (nf4*)(outA + b1) + lane);
        __builtin_nontemporal_store(w4, (nf4*)(outW + b1) + lane);
    }

    // ---- per-thread contributions to the 10 per-ray sums ----
    float acc[10];
#pragma unroll
    for (int c = 0; c < 3; ++c) {
        float ad = 0.0f, ab = 0.0f, ar = 0.0f;
#pragma unroll
        for (int i = 0; i < 4; ++i) {
            ad += exp2f(-(off[1 + c] + ser[1 + c][i])) * aorv[i * 3 + c];
            ab += exp2f(-(off[4 + c] + ser[4 + c][i])) * mamr[i * 3 + c];
            ar += T[i] * aorv[i * 3 + c];
        }
        acc[c]     = ad;   // direct
        acc[3 + c] = ab;   // backscatter
        acc[6 + c] = ar;   // restored
    }
    acc[9] = w[0] + w[1] + w[2] + w[3];      // object mask

    // ---- 10-wide interleaved DPP reduction (lane 63 holds totals) ----
    wave_iscan<10>(acc);

    if (lane == 63) {
        float* rgb  = out;                                  // [R,3]
        float* rest = out + (size_t)3 * R;                  // [R,3]
        float* dir  = out + (size_t)6 * R;                  // [R,3]
        float* bs   = out + (size_t)9 * R;                  // [R,3]
        float* dc0  = out + (size_t)12 * R + 3 * RS;
        float* bc0  = dc0 + (size_t)3 * R;
        float* mask = bc0 + (size_t)3 * R;                  // [R,1]
#pragma unroll
        for (int c = 0; c < 3; ++c) {
            const float d = acc[c], b = acc[3 + c];
            rgb[ray * 3 + c]  = clip01(d + b);
            dir[ray * 3 + c]  = clip01(d);
            bs[ray * 3 + c]   = clip01(b);
            rest[ray * 3 + c] = clip01(acc[6 + c]);
        }
        mask[ray] = clip01(acc[9]);
    }
    if (lane == 0) {
        float* dc0 = out + (size_t)12 * R + 3 * RS;
        float* bc0 = dc0 + (size_t)3 * R;
#pragma unroll
        for (int c = 0; c < 3; ++c) {
            dc0[ray * 3 + c] = dcv[c];   // raw sample-0 coeffs (unscaled)
            bc0[ray * 3 + c] = bcv[c];
        }
    }
}

extern "C" void kernel_launch(void* const* d_in, const int* in_sizes, int n_in,
                              void* d_out, int out_size, void* d_ws, size_t ws_size,
                              hipStream_t stream) {
    const float* orgb = (const float*)d_in[0];
    const float* mrgb = (const float*)d_in[1];
    const float* dc   = (const float*)d_in[2];
    const float* bc   = (const float*)d_in[3];
    const float* den  = (const float*)d_in[4];
    const float* del  = (const float*)d_in[5];

    const int S = 256;
    const int R = in_sizes[0] / (S * 3);

    dim3 block(256);                 // 4 waves = 4 independent rays per block
    dim3 grid((R + 3) / 4);
    seathru_render<<<grid, block, 0, stream>>>(orgb, mrgb, dc, bc, den, del,
                                               (float*)d_out, R);
}

// Round 8
// 235.378 us; speedup vs baseline: 1.0414x; 1.0235x over previous
//
#include <hip/hip_runtime.h>

// SeaThru-NeRF RGB renderer forward pass, round 11.
//
// LEDGER (6 kernels): shuffle/LDS/DPP/pins/asm-burst-persistent/NT-stores;
// occupancy 19-71%, VGPR 24-48, MLP forced 14-wide, perfect line coverage
// (R4), NT stores (R10) -- ALL pin at 96-105us. Invariant: delivered bytes
// (235MB reads + 51MB writes) / 97us ~= 2.9 TB/s combined L3+HBM, with HBM
// at only 1.7 TB/s (L3 serves ~120MB of reads; input set ~fits 256MB L3 and
// the write stream cyclically evicts half). Wave lifetime 6.7us ~= 17 x
// 900cyc serialized round-trips: a DELIVERY-side cap, not issue-side.
//
// REMAINING HYPOTHESES: (a) mixed L3-hit/HBM-miss traffic serializes in the
// memory-side cache; (b) HBM rate-capped ~1.7 TB/s (DVFS -- platform);
// (c) per-CU MSHR concurrency cap (256CU x ~32 lines x 128B / 375ns ~= 2.8
// TB/s -- matches). EXPERIMENT: NONTEMPORAL LOADS on all 6 input streams ->
// pure HBM streaming, the regime where 6.3 TB/s was measured. Outcomes:
// FETCH->~230MB + dur down = (a); dur up ~140us = (b, declare); dur flat
// while moving 286MB pure-HBM = (c, request-side exhausted, declare).
//
// Compute core = R5 exactly (best measured; DPP scans, fused log2 domain).

#define LOG2E 1.4426950408889634f

typedef float nf4 __attribute__((ext_vector_type(4)));   // native vec4

__device__ __forceinline__ float clip01(float x) {
    return fminf(fmaxf(x, 0.0f), 1.0f);
}

// DPP move (old=0, bank_mask=0xf). Template params keep builtin args ICE.
template <int CTRL, int ROW_MASK, bool BND>
__device__ __forceinline__ float dpp_mov(float v) {
    return __int_as_float(__builtin_amdgcn_update_dpp(
        0, __float_as_int(v), CTRL, ROW_MASK, 0xf, BND));
}

// N-wide interleaved wave64 INCLUSIVE add-scan, entirely on the VALU pipe.
template <int N>
__device__ __forceinline__ void wave_iscan(float (&v)[N]) {
#pragma unroll
    for (int j = 0; j < N; ++j) v[j] += dpp_mov<0x111, 0xf, true>(v[j]);
#pragma unroll
    for (int j = 0; j < N; ++j) v[j] += dpp_mov<0x112, 0xf, true>(v[j]);
#pragma unroll
    for (int j = 0; j < N; ++j) v[j] += dpp_mov<0x114, 0xf, true>(v[j]);
#pragma unroll
    for (int j = 0; j < N; ++j) v[j] += dpp_mov<0x118, 0xf, true>(v[j]);
#pragma unroll
    for (int j = 0; j < N; ++j) v[j] += dpp_mov<0x142, 0xa, false>(v[j]);
#pragma unroll
    for (int j = 0; j < N; ++j) v[j] += dpp_mov<0x143, 0xc, false>(v[j]);
}

__global__ __launch_bounds__(256, 4) void seathru_render(
    const float* __restrict__ g_orgb,   // [R,S,3] object_rgbs
    const float* __restrict__ g_mrgb,   // [R,S,3] medium_rgbs
    const float* __restrict__ g_dc,     // [R,S,3] direct_coeffs
    const float* __restrict__ g_bc,     // [R,S,3] backscatter_coeffs
    const float* __restrict__ g_den,    // [R,S,1] densities
    const float* __restrict__ g_del,    // [R,S,1] deltas
    float* __restrict__ out, int R)
{
    const int S = 256;
    const int ray  = blockIdx.x * 4 + (threadIdx.x >> 6);  // wave-uniform
    const int lane = threadIdx.x & 63;
    if (ray >= R) return;

    const size_t b3 = (size_t)ray * (S * 3);
    const size_t b1 = (size_t)ray * S;
    const size_t RS = (size_t)R * S;

    // ---- NONTEMPORAL loads: lane owns samples 4*lane .. 4*lane+3 ----
    nf4 dl4 = __builtin_nontemporal_load((const nf4*)(g_del + b1) + lane);
    nf4 dn4 = __builtin_nontemporal_load((const nf4*)(g_den + b1) + lane);

    float dcv[12], bcv[12], orv[12], mrv[12];
    {
        const nf4* p = (const nf4*)(g_dc + b3) + lane * 3;
        *(nf4*)&dcv[0] = __builtin_nontemporal_load(p + 0);
        *(nf4*)&dcv[4] = __builtin_nontemporal_load(p + 1);
        *(nf4*)&dcv[8] = __builtin_nontemporal_load(p + 2);
    }
    {
        const nf4* p = (const nf4*)(g_bc + b3) + lane * 3;
        *(nf4*)&bcv[0] = __builtin_nontemporal_load(p + 0);
        *(nf4*)&bcv[4] = __builtin_nontemporal_load(p + 1);
        *(nf4*)&bcv[8] = __builtin_nontemporal_load(p + 2);
    }
    {
        const nf4* p = (const nf4*)(g_orgb + b3) + lane * 3;
        *(nf4*)&orv[0] = __builtin_nontemporal_load(p + 0);
        *(nf4*)&orv[4] = __builtin_nontemporal_load(p + 1);
        *(nf4*)&orv[8] = __builtin_nontemporal_load(p + 2);
    }
    {
        const nf4* p = (const nf4*)(g_mrgb + b3) + lane * 3;
        *(nf4*)&mrv[0] = __builtin_nontemporal_load(p + 0);
        *(nf4*)&mrv[4] = __builtin_nontemporal_load(p + 1);
        *(nf4*)&mrv[8] = __builtin_nontemporal_load(p + 2);
    }

    const float del[4] = {dl4.x * LOG2E, dl4.y * LOG2E, dl4.z * LOG2E, dl4.w * LOG2E};
    const float den[4] = {dn4.x, dn4.y, dn4.z, dn4.w};

    // ---- thread-local pre-pass: consume orv/mrv immediately ----
    float dd[4], alpha[4];
#pragma unroll
    for (int i = 0; i < 4; ++i) {
        dd[i]    = del[i] * den[i];
        alpha[i] = 1.0f - exp2f(-dd[i]);
    }

    float aorv[12];   // alpha * object_rgb
    float mamr[12];   // medium_alpha * medium_rgb
#pragma unroll
    for (int i = 0; i < 4; ++i) {
#pragma unroll
        for (int c = 0; c < 3; ++c) {
            aorv[i * 3 + c] = alpha[i] * orv[i * 3 + c];
            const float bsd = bcv[i * 3 + c] * del[i];
            mamr[i * 3 + c] = (1.0f - exp2f(-bsd)) * mrv[i * 3 + c];
        }
    }

    // ---- serial (intra-thread) exclusive prefixes for the 7 fused scans ----
    float ser[7][4];
    float run[7];
#pragma unroll
    for (int q = 0; q < 7; ++q) run[q] = 0.0f;
#pragma unroll
    for (int i = 0; i < 4; ++i) {
        ser[0][i] = run[0]; run[0] += dd[i];
#pragma unroll
        for (int c = 0; c < 3; ++c) {
            ser[1 + c][i] = run[1 + c]; run[1 + c] += dd[i] + dcv[i * 3 + c] * del[i];
            ser[4 + c][i] = run[4 + c]; run[4 + c] += dd[i] + bcv[i * 3 + c] * del[i];
        }
    }

    // ---- 7-wide interleaved DPP wave scan of the thread totals ----
    float sc[7];
#pragma unroll
    for (int q = 0; q < 7; ++q) sc[q] = run[q];
    wave_iscan<7>(sc);
    float off[7];
#pragma unroll
    for (int q = 0; q < 7; ++q) off[q] = sc[q] - run[q];   // wave-exclusive

    // ---- per-sample outputs: NT stores (kept from R10, neutral) ----
    float T[4], w[4];
#pragma unroll
    for (int i = 0; i < 4; ++i) {
        T[i] = exp2f(-(off[0] + ser[0][i]));
        w[i] = T[i] * alpha[i];
    }

    float* outT = out + (size_t)12 * R;      // object_transmittance [R,S]
    float* outA = outT + RS;                 // object_alphas
    float* outW = outA + RS;                 // object_weights
    {
        nf4 t4 = {T[0], T[1], T[2], T[3]};
        nf4 a4 = {alpha[0], alpha[1], alpha[2], alpha[3]};
        nf4 w4 = {w[0], w[1], w[2], w[3]};
        __builtin_nontemporal_store(t4, (nf4*)(outT + b1) + lane);
        __builtin_nontemporal_store(a4, (nf4*)(outA + b1) + lane);
        __builtin_nontemporal_store(w4, (nf4*)(outW + b1) + lane);
    }

    // ---- per-thread contributions to the 10 per-ray sums ----
    float acc[10];
#pragma unroll
    for (int c = 0; c < 3; ++c) {
        float ad = 0.0f, ab = 0.0f, ar = 0.0f;
#pragma unroll
        for (int i = 0; i < 4; ++i) {
            ad += exp2f(-(off[1 + c] + ser[1 + c][i])) * aorv[i * 3 + c];
            ab += exp2f(-(off[4 + c] + ser[4 + c][i])) * mamr[i * 3 + c];
            ar += T[i] * aorv[i * 3 + c];
        }
        acc[c]     = ad;   // direct
        acc[3 + c] = ab;   // backscatter
        acc[6 + c] = ar;   // restored
    }
    acc[9] = w[0] + w[1] + w[2] + w[3];      // object mask

    // ---- 10-wide interleaved DPP reduction (lane 63 holds totals) ----
    wave_iscan<10>(acc);

    if (lane == 63) {
        float* rgb  = out;                                  // [R,3]
        float* rest = out + (size_t)3 * R;                  // [R,3]
        float* dir  = out + (size_t)6 * R;                  // [R,3]
        float* bs   = out + (size_t)9 * R;                  // [R,3]
        float* dc0  = out + (size_t)12 * R + 3 * RS;
        float* bc0  = dc0 + (size_t)3 * R;
        float* mask = bc0 + (size_t)3 * R;                  // [R,1]
#pragma unroll
        for (int c = 0; c < 3; ++c) {
            const float d = acc[c], b = acc[3 + c];
            rgb[ray * 3 + c]  = clip01(d + b);
            dir[ray * 3 + c]  = clip01(d);
            bs[ray * 3 + c]   = clip01(b);
            rest[ray * 3 + c] = clip01(acc[6 + c]);
        }
        mask[ray] = clip01(acc[9]);
    }
    if (lane == 0) {
        float* dc0 = out + (size_t)12 * R + 3 * RS;
        float* bc0 = dc0 + (size_t)3 * R;
#pragma unroll
        for (int c = 0; c < 3; ++c) {
            dc0[ray * 3 + c] = dcv[c];   // raw sample-0 coeffs (unscaled)
            bc0[ray * 3 + c] = bcv[c];
        }
    }
}

extern "C" void kernel_launch(void* const* d_in, const int* in_sizes, int n_in,
                              void* d_out, int out_size, void* d_ws, size_t ws_size,
                              hipStream_t stream) {
    const float* orgb = (const float*)d_in[0];
    const float* mrgb = (const float*)d_in[1];
    const float* dc   = (const float*)d_in[2];
    const float* bc   = (const float*)d_in[3];
    const float* den  = (const float*)d_in[4];
    const float* del  = (const float*)d_in[5];

    const int S = 256;
    const int R = in_sizes[0] / (S * 3);

    dim3 block(256);                 // 4 waves = 4 independent rays per block
    dim3 grid((R + 3) / 4);
    seathru_render<<<grid, block, 0, stream>>>(orgb, mrgb, dc, bc, den, del,
                                               (float*)d_out, R);
}